// Round 1
// baseline (69.183 us; speedup 1.0000x reference)
//
#include <hip/hip_runtime.h>

// Output = 0.5 * mean(sigmoid(conv2d_valid(data, w) + b)) broadcast to 256 elems.
// Quantum term is identically 0: RX(pi) = -i*X (global phase on the uniform
// state), CX is a basis permutation -> final probs uniform -> 2*P(q0=1)-1 = 0.

constexpr int IMG   = 64;
constexpr int OUTW  = 61;                 // 64 - 4 + 1
constexpr int NPIX  = OUTW * OUTW;        // 3721
constexpr int BATCH = 256;
constexpr float INV_TOTAL = 1.0f / (float)(BATCH * NPIX);

__global__ __launch_bounds__(256) void conv_sig_reduce(
    const float* __restrict__ data, const float* __restrict__ w,
    const float* __restrict__ bias, float* __restrict__ out,
    float* __restrict__ ws)
{
    __shared__ float img[IMG * IMG];      // 16 KB image tile
    __shared__ float wsm[16];
    __shared__ float wave_part[4];
    __shared__ float result;
    __shared__ int   last;

    const int tid = threadIdx.x;

    // Stage image into LDS: 1024 float4 over 256 threads (coalesced 16B/lane).
    const float* src = data + (size_t)blockIdx.x * (IMG * IMG);
    #pragma unroll
    for (int i = 0; i < 4; ++i)
        reinterpret_cast<float4*>(img)[tid + 256 * i] =
            reinterpret_cast<const float4*>(src)[tid + 256 * i];
    if (tid < 16) wsm[tid] = w[tid];
    __syncthreads();

    const float b0 = bias[0];
    float acc = 0.0f;
    for (int idx = tid; idx < NPIX; idx += 256) {
        const int i = idx / OUTW;
        const int j = idx - i * OUTW;
        float s = b0;
        #pragma unroll
        for (int ki = 0; ki < 4; ++ki) {
            #pragma unroll
            for (int kj = 0; kj < 4; ++kj)
                s = fmaf(img[(i + ki) * IMG + (j + kj)], wsm[ki * 4 + kj], s);
        }
        acc += 1.0f / (1.0f + __expf(-s));   // sigmoid
    }

    // Wave-64 shuffle reduction, then cross-wave via LDS.
    #pragma unroll
    for (int off = 32; off > 0; off >>= 1)
        acc += __shfl_down(acc, off, 64);
    if ((tid & 63) == 0) wave_part[tid >> 6] = acc;
    __syncthreads();

    if (tid == 0) {
        float t = wave_part[0] + wave_part[1] + wave_part[2] + wave_part[3];
        atomicAdd(ws, t);                              // device-scope
        __threadfence();
        unsigned prev = atomicAdd(reinterpret_cast<unsigned*>(ws) + 1, 1u);
        if (prev == gridDim.x - 1) {                   // we are the last block
            float total = atomicAdd(ws, 0.0f);         // atomic read: all adds visible
            result = 0.5f * (total * INV_TOTAL);
            last = 1;
        } else {
            last = 0;
        }
    }
    __syncthreads();
    if (last) out[tid] = result;                       // 256 threads -> 256 outputs
}

extern "C" void kernel_launch(void* const* d_in, const int* in_sizes, int n_in,
                              void* d_out, int out_size, void* d_ws, size_t ws_size,
                              hipStream_t stream)
{
    const float* data = (const float*)d_in[0];   // (256,1,64,64) f32
    const float* w    = (const float*)d_in[1];   // (1,1,4,4) f32
    const float* bias = (const float*)d_in[2];   // (1,) f32
    float* out = (float*)d_out;                  // 256 f32
    float* ws  = (float*)d_ws;

    // ws[0] = float accumulator, ws[1] = arrival counter. Re-zero every call
    // (harness poisons ws with 0xAA before each timed launch).
    hipMemsetAsync(ws, 0, 8, stream);
    conv_sig_reduce<<<BATCH, 256, 0, stream>>>(data, w, bias, out, ws);
}

// Round 2
// 61.632 us; speedup vs baseline: 1.1225x; 1.1225x over previous
//
#include <hip/hip_runtime.h>

// out[0..255] = 0.5 * mean(sigmoid(conv2d_valid(data, w4x4) + b))
// Quantum term is identically 0: RX(pi) = -i*X acts as a global phase on the
// uniform H^16|0> state, CX is a basis permutation -> uniform probs ->
// 2*P(q0=1)-1 = 0 exactly.
//
// Two dispatches, no atomics, no workspace init (every ws slot written):
//   k1: 256 blocks, block b -> ws[b] = partial sigmoid-sum of image b
//   k2: 1 block, reduce 256 partials, broadcast to out[0..255]

constexpr int IMG   = 64;
constexpr int OUTW  = 61;                 // 64 - 4 + 1
constexpr int NPIX  = OUTW * OUTW;        // 3721
constexpr int BATCH = 256;
constexpr float INV_TOTAL = 1.0f / (float)(BATCH * NPIX);

__global__ __launch_bounds__(256) void conv_sig_partial(
    const float* __restrict__ data, const float* __restrict__ w,
    const float* __restrict__ bias, float* __restrict__ ws)
{
    __shared__ float img[IMG * IMG];      // 16 KB image tile
    __shared__ float wsm[16];
    __shared__ float wave_part[4];

    const int tid = threadIdx.x;

    // Stage image into LDS: 1024 float4 over 256 threads (coalesced 16B/lane).
    const float* src = data + (size_t)blockIdx.x * (IMG * IMG);
    #pragma unroll
    for (int i = 0; i < 4; ++i)
        reinterpret_cast<float4*>(img)[tid + 256 * i] =
            reinterpret_cast<const float4*>(src)[tid + 256 * i];
    if (tid < 16) wsm[tid] = w[tid];
    __syncthreads();

    const float b0 = bias[0];
    float acc = 0.0f;
    for (int idx = tid; idx < NPIX; idx += 256) {
        const int i = idx / OUTW;         // magic-mul, cheap
        const int j = idx - i * OUTW;
        float s = b0;
        #pragma unroll
        for (int ki = 0; ki < 4; ++ki) {
            #pragma unroll
            for (int kj = 0; kj < 4; ++kj)
                s = fmaf(img[(i + ki) * IMG + (j + kj)], wsm[ki * 4 + kj], s);
        }
        acc += 1.0f / (1.0f + __expf(-s));   // sigmoid
    }

    // Wave-64 shuffle reduction, then cross-wave via LDS.
    #pragma unroll
    for (int off = 32; off > 0; off >>= 1)
        acc += __shfl_down(acc, off, 64);
    if ((tid & 63) == 0) wave_part[tid >> 6] = acc;
    __syncthreads();

    if (tid == 0)
        ws[blockIdx.x] = wave_part[0] + wave_part[1] + wave_part[2] + wave_part[3];
}

__global__ __launch_bounds__(256) void reduce_broadcast(
    const float* __restrict__ ws, float* __restrict__ out)
{
    __shared__ float wave_part[4];
    __shared__ float result;

    const int tid = threadIdx.x;
    float acc = ws[tid];
    #pragma unroll
    for (int off = 32; off > 0; off >>= 1)
        acc += __shfl_down(acc, off, 64);
    if ((tid & 63) == 0) wave_part[tid >> 6] = acc;
    __syncthreads();
    if (tid == 0) {
        float total = wave_part[0] + wave_part[1] + wave_part[2] + wave_part[3];
        result = 0.5f * (total * INV_TOTAL);
    }
    __syncthreads();
    out[tid] = result;
}

extern "C" void kernel_launch(void* const* d_in, const int* in_sizes, int n_in,
                              void* d_out, int out_size, void* d_ws, size_t ws_size,
                              hipStream_t stream)
{
    const float* data = (const float*)d_in[0];   // (256,1,64,64) f32
    const float* w    = (const float*)d_in[1];   // (1,1,4,4) f32
    const float* bias = (const float*)d_in[2];   // (1,) f32
    float* out = (float*)d_out;                  // 256 f32
    float* ws  = (float*)d_ws;                   // 256 partials, all overwritten

    conv_sig_partial<<<BATCH, 256, 0, stream>>>(data, w, bias, ws);
    reduce_broadcast<<<1, 256, 0, stream>>>(ws, out);
}

// Round 3
// 59.972 us; speedup vs baseline: 1.1536x; 1.0277x over previous
//
#include <hip/hip_runtime.h>

// out[0..255] = 0.5 * mean(sigmoid(conv2d_valid(data, w4x4) + b))
// Quantum term is identically 0: RX(pi) = -i*X acts as a global phase on the
// uniform H^16|0> state, CX is a basis permutation -> uniform probs ->
// 2*P(q0=1)-1 = 0 exactly.
//
// k1: 256 blocks, block b -> ws[b] = partial sigmoid-sum of image b.
//     4 adjacent pixels per step via two aligned float4 LDS reads per kernel
//     row (8x ds_read_b128 + 64 FMA per group vs 64 scalar reads).
// k2: 1 block, reduce 256 partials, broadcast to out[0..255].

constexpr int IMG   = 64;
constexpr int OUTW  = 61;                   // 64 - 4 + 1
constexpr int NPIX  = OUTW * OUTW;          // 3721
constexpr int BATCH = 256;
constexpr int GPR   = 16;                   // 4-pixel groups per row (j0 = 4g)
constexpr int NGRP  = OUTW * GPR;           // 976
constexpr float INV_TOTAL = 1.0f / (float)(BATCH * NPIX);

__device__ __forceinline__ float sigf(float s) {
    return __builtin_amdgcn_rcpf(1.0f + __expf(-s));
}

__global__ __launch_bounds__(256) void conv_sig_partial(
    const float* __restrict__ data, const float* __restrict__ w,
    const float* __restrict__ bias, float* __restrict__ ws)
{
    __shared__ __align__(16) float img[IMG * IMG + 4];  // +4 pad: g=15 second f4
    __shared__ float wsm[16];
    __shared__ float wave_part[4];

    const int tid = threadIdx.x;

    // Stage image: 1024 float4 over 256 threads (coalesced 16B/lane).
    const float* src = data + (size_t)blockIdx.x * (IMG * IMG);
    #pragma unroll
    for (int i = 0; i < 4; ++i)
        reinterpret_cast<float4*>(img)[tid + 256 * i] =
            reinterpret_cast<const float4*>(src)[tid + 256 * i];
    if (tid < 16) wsm[tid] = w[tid];
    if (tid >= 16 && tid < 20) img[IMG * IMG + tid - 16] = 0.0f;  // pad
    __syncthreads();

    // Weights to registers (uniform LDS reads broadcast, conflict-free).
    float wr[16];
    #pragma unroll
    for (int k = 0; k < 16; ++k) wr[k] = wsm[k];
    const float b0 = bias[0];

    const float4* imgv = reinterpret_cast<const float4*>(img);
    float acc = 0.0f;

    for (int gidx = tid; gidx < NGRP; gidx += 256) {
        const int i = gidx >> 4;          // output row
        const int g = gidx & 15;          // 4-pixel group; j0 = 4g
        float s0 = b0, s1 = b0, s2 = b0, s3 = b0;
        #pragma unroll
        for (int ki = 0; ki < 4; ++ki) {
            const int rb = (i + ki) * (IMG / 4) + g;
            const float4 a = imgv[rb];        // cols 4g .. 4g+3
            const float4 c = imgv[rb + 1];    // cols 4g+4 .. 4g+7 (pad-safe)
            const float w0 = wr[ki * 4 + 0], w1 = wr[ki * 4 + 1];
            const float w2 = wr[ki * 4 + 2], w3 = wr[ki * 4 + 3];
            s0 = fmaf(a.x, w0, fmaf(a.y, w1, fmaf(a.z, w2, fmaf(a.w, w3, s0))));
            s1 = fmaf(a.y, w0, fmaf(a.z, w1, fmaf(a.w, w2, fmaf(c.x, w3, s1))));
            s2 = fmaf(a.z, w0, fmaf(a.w, w1, fmaf(c.x, w2, fmaf(c.y, w3, s2))));
            s3 = fmaf(a.w, w0, fmaf(c.x, w1, fmaf(c.y, w2, fmaf(c.z, w3, s3))));
        }
        if (g == 15) {                    // j0=60: only pixel 0 in range (OUTW=61)
            acc += sigf(s0);
        } else {
            acc += sigf(s0) + sigf(s1) + sigf(s2) + sigf(s3);
        }
    }

    // Wave-64 shuffle reduction, then cross-wave via LDS.
    #pragma unroll
    for (int off = 32; off > 0; off >>= 1)
        acc += __shfl_down(acc, off, 64);
    if ((tid & 63) == 0) wave_part[tid >> 6] = acc;
    __syncthreads();

    if (tid == 0)
        ws[blockIdx.x] = wave_part[0] + wave_part[1] + wave_part[2] + wave_part[3];
}

__global__ __launch_bounds__(256) void reduce_broadcast(
    const float* __restrict__ ws, float* __restrict__ out)
{
    __shared__ float wave_part[4];
    __shared__ float result;

    const int tid = threadIdx.x;
    float acc = ws[tid];
    #pragma unroll
    for (int off = 32; off > 0; off >>= 1)
        acc += __shfl_down(acc, off, 64);
    if ((tid & 63) == 0) wave_part[tid >> 6] = acc;
    __syncthreads();
    if (tid == 0) {
        float total = wave_part[0] + wave_part[1] + wave_part[2] + wave_part[3];
        result = 0.5f * (total * INV_TOTAL);
    }
    __syncthreads();
    out[tid] = result;
}

extern "C" void kernel_launch(void* const* d_in, const int* in_sizes, int n_in,
                              void* d_out, int out_size, void* d_ws, size_t ws_size,
                              hipStream_t stream)
{
    const float* data = (const float*)d_in[0];   // (256,1,64,64) f32
    const float* w    = (const float*)d_in[1];   // (1,1,4,4) f32
    const float* bias = (const float*)d_in[2];   // (1,) f32
    float* out = (float*)d_out;                  // 256 f32
    float* ws  = (float*)d_ws;                   // 256 partials, all overwritten

    conv_sig_partial<<<BATCH, 256, 0, stream>>>(data, w, bias, ws);
    reduce_broadcast<<<1, 256, 0, stream>>>(ws, out);
}